// Round 3
// baseline (13715.280 us; speedup 1.0000x reference)
//
#include <hip/hip_runtime.h>
#include <cmath>

namespace {

constexpr int Tn = 64;
constexpr int Bn = 512;
constexpr int Xn = 784;
constexpr int XnP = 800;
constexpr int Fn = 64;
constexpr int Zn = 64;
constexpr int Hn = 512;

typedef unsigned short us;
typedef __attribute__((ext_vector_type(8))) short bf16x8;
typedef __attribute__((ext_vector_type(4))) float f32x4;

__device__ __forceinline__ us f2b(float v) {
  unsigned int u = __float_as_uint(v);
  return (us)((u + 0x7FFFu + ((u >> 16) & 1u)) >> 16);
}
__device__ __forceinline__ float b2f(us u) { return __uint_as_float(((unsigned int)u) << 16); }
__device__ __forceinline__ float sigmf(float v) { return 1.0f / (1.0f + __expf(-v)); }
__device__ __forceinline__ float splusf(float v) {
  return v > 0.0f ? (v + log1pf(__expf(-v))) : log1pf(__expf(v));
}
__device__ __forceinline__ float block_sum(float v, float* red) {
  #pragma unroll
  for (int off = 32; off > 0; off >>= 1) v += __shfl_down(v, off, 64);
  if ((threadIdx.x & 63) == 0) red[threadIdx.x >> 6] = v;
  __syncthreads();
  float s = 0.0f;
  if (threadIdx.x == 0) s = red[0] + red[1] + red[2] + red[3];
  return s;
}

// ---- converters ----
__global__ void cvt(const float* __restrict__ s, us* __restrict__ d, int n) {
  int i = blockIdx.x * 256 + threadIdx.x;
  if (i < n) d[i] = f2b(s[i]);
}
__global__ void cvt_pad(const float* __restrict__ s, us* __restrict__ d, int C, int Cp, int n) {
  int i = blockIdx.x * 256 + threadIdx.x;
  if (i < n) {
    int r = i / Cp, c = i - r * Cp;
    d[i] = (c < C) ? f2b(s[(size_t)r * C + c]) : (us)0;
  }
}

// ================= tile device functions =================
// 64x64 GEMM tile: C = act( sum_seg A_seg . W_seg^T + bias ). sm: 2x2560 us.
template <int NSEG, bool RELU>
__device__ __forceinline__ void tile_gemm(
    int bx, int by,
    const us* __restrict__ A0, const us* __restrict__ W0, int ldw0, int K0,
    const us* __restrict__ A1, const us* __restrict__ W1, int ldw1, int K1,
    const us* __restrict__ A2, const us* __restrict__ W2, int ldw2, int K2,
    const float* __restrict__ bias, us* __restrict__ C, int ldc, us* sm)
{
  us* As = sm; us* Bs = sm + 2560;
  const int tid = threadIdx.x, srow = tid >> 2, scb = (tid & 3) * 8;
  const int lane = tid & 63, w = tid >> 6, l15 = lane & 15, q = lane >> 4;
  const int m0 = by * 64, n0 = bx * 64;
  f32x4 acc[4];
  #pragma unroll
  for (int j = 0; j < 4; ++j) acc[j] = (f32x4){0.f, 0.f, 0.f, 0.f};
  for (int seg = 0; seg < NSEG; ++seg) {
    const us* A = (seg == 0) ? A0 : (seg == 1) ? A1 : A2;
    const us* W = (seg == 0) ? W0 : (seg == 1) ? W1 : W2;
    const int ldw = (seg == 0) ? ldw0 : (seg == 1) ? ldw1 : ldw2;
    const int K   = (seg == 0) ? K0 : (seg == 1) ? K1 : K2;
    const us* ap = A + (size_t)(m0 + srow) * K + scb;
    const us* wp = W + (size_t)(n0 + srow) * ldw + scb;
    for (int k0 = 0; k0 < K; k0 += 32) {
      uint4 av = *(const uint4*)(ap + k0);
      uint4 wv = *(const uint4*)(wp + k0);
      __syncthreads();
      *(uint4*)&As[srow * 40 + scb] = av;
      *(uint4*)&Bs[srow * 40 + scb] = wv;
      __syncthreads();
      bf16x8 a = *(const bf16x8*)&As[(w * 16 + l15) * 40 + q * 8];
      #pragma unroll
      for (int j = 0; j < 4; ++j) {
        bf16x8 b = *(const bf16x8*)&Bs[(j * 16 + l15) * 40 + q * 8];
        acc[j] = __builtin_amdgcn_mfma_f32_16x16x32_bf16(a, b, acc[j], 0, 0, 0);
      }
    }
  }
  #pragma unroll
  for (int j = 0; j < 4; ++j) {
    const int col = n0 + j * 16 + l15;
    const float bv = bias[col];
    #pragma unroll
    for (int r = 0; r < 4; ++r) {
      const int row = m0 + w * 16 + q * 4 + r;
      float v = acc[j][r] + bv;
      if (RELU) v = fmaxf(v, 0.f);
      C[(size_t)row * ldc + col] = f2b(v);
    }
  }
}

// GRU 64x64 tile. sm: 4x2560 us.
template <int NSEGI>
__device__ __forceinline__ void tile_gru(
    int bx, int by,
    const us* __restrict__ A0, const us* __restrict__ A1, const us* __restrict__ A2,
    const us* __restrict__ Wih, int ldwih,
    const us* __restrict__ hprev, const us* __restrict__ Whh,
    const float* __restrict__ bih, const float* __restrict__ bhh,
    us* __restrict__ hnew, us* sm)
{
  us* Asm = sm; us* Rs = sm + 2560; us* Zs = sm + 5120; us* Ns = sm + 7680;
  const int tid = threadIdx.x, srow = tid >> 2, scb = (tid & 3) * 8;
  const int lane = tid & 63, w = tid >> 6, l15 = lane & 15, q = lane >> 4;
  const int m0 = by * 64, c0 = bx * 64;
  f32x4 aR[4], aZ[4], aI[4], aH[4];
  #pragma unroll
  for (int j = 0; j < 4; ++j) {
    aR[j] = (f32x4){0.f, 0.f, 0.f, 0.f}; aZ[j] = aR[j]; aI[j] = aR[j]; aH[j] = aR[j];
  }
  for (int seg = 0; seg <= NSEGI; ++seg) {
    const bool hseg = (seg == NSEGI);
    const us* A  = hseg ? hprev : ((seg == 0) ? A0 : (seg == 1) ? A1 : A2);
    const us* Wb = hseg ? Whh : Wih;
    const int ldw  = hseg ? Hn : ldwih;
    const int coff = hseg ? 0 : seg * Hn;
    const us* ap = A + (size_t)(m0 + srow) * Hn + scb;
    const us* wr = Wb + (size_t)(c0 + srow) * ldw + coff + scb;
    const us* wz = wr + (size_t)Hn * ldw;
    const us* wn = wz + (size_t)Hn * ldw;
    for (int k0 = 0; k0 < Hn; k0 += 32) {
      uint4 av = *(const uint4*)(ap + k0);
      uint4 rv = *(const uint4*)(wr + k0);
      uint4 zv = *(const uint4*)(wz + k0);
      uint4 nv = *(const uint4*)(wn + k0);
      __syncthreads();
      *(uint4*)&Asm[srow * 40 + scb] = av;
      *(uint4*)&Rs[srow * 40 + scb] = rv;
      *(uint4*)&Zs[srow * 40 + scb] = zv;
      *(uint4*)&Ns[srow * 40 + scb] = nv;
      __syncthreads();
      bf16x8 a = *(const bf16x8*)&Asm[(w * 16 + l15) * 40 + q * 8];
      #pragma unroll
      for (int j = 0; j < 4; ++j) {
        bf16x8 br = *(const bf16x8*)&Rs[(j * 16 + l15) * 40 + q * 8];
        bf16x8 bz = *(const bf16x8*)&Zs[(j * 16 + l15) * 40 + q * 8];
        bf16x8 bn = *(const bf16x8*)&Ns[(j * 16 + l15) * 40 + q * 8];
        aR[j] = __builtin_amdgcn_mfma_f32_16x16x32_bf16(a, br, aR[j], 0, 0, 0);
        aZ[j] = __builtin_amdgcn_mfma_f32_16x16x32_bf16(a, bz, aZ[j], 0, 0, 0);
        if (hseg) aH[j] = __builtin_amdgcn_mfma_f32_16x16x32_bf16(a, bn, aH[j], 0, 0, 0);
        else      aI[j] = __builtin_amdgcn_mfma_f32_16x16x32_bf16(a, bn, aI[j], 0, 0, 0);
      }
    }
  }
  #pragma unroll
  for (int j = 0; j < 4; ++j) {
    const int c = c0 + j * 16 + l15;
    const float bR = bih[c] + bhh[c];
    const float bZ = bih[Hn + c] + bhh[Hn + c];
    const float bI = bih[2 * Hn + c];
    const float bH = bhh[2 * Hn + c];
    #pragma unroll
    for (int r = 0; r < 4; ++r) {
      const int m = m0 + w * 16 + q * 4 + r;
      const float h = b2f(hprev[(size_t)m * Hn + c]);
      const float rg = sigmf(aR[j][r] + bR);
      const float zg = sigmf(aZ[j][r] + bZ);
      const float ng = tanhf(aI[j][r] + bI + rg * (aH[j][r] + bH));
      hnew[(size_t)m * Hn + c] = f2b((1.0f - zg) * ng + zg * h);
    }
  }
}

// decoder GEMM tile + fused BCE reduction. smemc: 10240 B tiles + 16 B red.
__device__ __forceinline__ void tile_nll(
    int bx, int by,
    const us* __restrict__ dec, const us* __restrict__ dmW,
    const float* __restrict__ dmb, const float* __restrict__ xt,
    float* __restrict__ nll, char* smemc)
{
  us* As = (us*)smemc; us* Bs = (us*)(smemc + 5120);
  float* red = (float*)(smemc + 10240);
  const int tid = threadIdx.x, srow = tid >> 2, scb = (tid & 3) * 8;
  const int lane = tid & 63, w = tid >> 6, l15 = lane & 15, q = lane >> 4;
  const int m0 = by * 64, n0 = bx * 64;
  f32x4 acc[4];
  #pragma unroll
  for (int j = 0; j < 4; ++j) acc[j] = (f32x4){0.f, 0.f, 0.f, 0.f};
  const int wrow = (n0 + srow < Xn) ? (n0 + srow) : (Xn - 1);
  const us* ap = dec + (size_t)(m0 + srow) * Hn + scb;
  const us* wp = dmW + (size_t)wrow * Hn + scb;
  for (int k0 = 0; k0 < Hn; k0 += 32) {
    uint4 av = *(const uint4*)(ap + k0);
    uint4 wv = *(const uint4*)(wp + k0);
    __syncthreads();
    *(uint4*)&As[srow * 40 + scb] = av;
    *(uint4*)&Bs[srow * 40 + scb] = wv;
    __syncthreads();
    bf16x8 a = *(const bf16x8*)&As[(w * 16 + l15) * 40 + q * 8];
    #pragma unroll
    for (int j = 0; j < 4; ++j) {
      bf16x8 b = *(const bf16x8*)&Bs[(j * 16 + l15) * 40 + q * 8];
      acc[j] = __builtin_amdgcn_mfma_f32_16x16x32_bf16(a, b, acc[j], 0, 0, 0);
    }
  }
  float sum = 0.0f;
  #pragma unroll
  for (int j = 0; j < 4; ++j) {
    const int n = n0 + j * 16 + l15;
    if (n < Xn) {
      const float bv = dmb[n];
      #pragma unroll
      for (int r = 0; r < 4; ++r) {
        const int m = m0 + w * 16 + q * 4 + r;
        const float a = acc[j][r] + bv;
        const float xv = xt[(size_t)m * Xn + n];
        sum += splusf(-a) + (1.0f - xv) * a;
      }
    }
  }
  const float s = block_sum(sum, red);
  if (tid == 0) atomicAdd(nll, s);
}

// "Tall" fused stat kernel: one block owns 64 full rows.
// pre = relu(IN@Wg^T + bg) built half-K at a time into LDS, stats MFMA'd from LDS.
// ENC=false: write mu->o_pm, sd->o_ps (fp32). ENC=true: zt=eps*sd+mu (LDS only),
// z_kld vs (pm_in,ps_in) -> kacc, phiz_out = relu(zt@pzW^T + pzb).
// smemc layout: zeL 33792 | ztL 9216 | As 5120 | B0 5120 | B1 5120 | red 16 = 58384 B
template <bool ENC>
__device__ void tall_stat(int vb,
    const us* __restrict__ IN, const us* __restrict__ Wg, const float* __restrict__ bg,
    const us* __restrict__ Wm, const float* __restrict__ bm,
    const us* __restrict__ Ws, const float* __restrict__ bs,
    const float* __restrict__ eps_t, const float* __restrict__ pm_in, const float* __restrict__ ps_in,
    float* __restrict__ o_pm, float* __restrict__ o_ps,
    const us* __restrict__ pzW, const float* __restrict__ pzb, us* __restrict__ phiz_out,
    float* __restrict__ kacc, char* smemc)
{
  us* zeL = (us*)smemc;                  // [64][264]
  us* ztL = (us*)(smemc + 33792);        // [64][72]
  us* As  = (us*)(smemc + 43008);
  us* B0  = (us*)(smemc + 48128);
  us* B1  = (us*)(smemc + 53248);
  float* red = (float*)(smemc + 58368);
  const int tid = threadIdx.x, srow = tid >> 2, scb = (tid & 3) * 8;
  const int lane = tid & 63, w = tid >> 6, l15 = lane & 15, q = lane >> 4;
  const int m0 = vb * 64;
  f32x4 accM[4], accS[4];
  #pragma unroll
  for (int j = 0; j < 4; ++j) { accM[j] = (f32x4){0.f, 0.f, 0.f, 0.f}; accS[j] = accM[j]; }

  for (int half = 0; half < 2; ++half) {
    // alpha: compute pre[64 x 256] for this half into zeL
    for (int cc = 0; cc < 4; ++cc) {
      const int n0 = half * 256 + cc * 64;
      f32x4 acc[4];
      #pragma unroll
      for (int j = 0; j < 4; ++j) acc[j] = (f32x4){0.f, 0.f, 0.f, 0.f};
      const us* ap = IN + (size_t)(m0 + srow) * 512 + scb;
      const us* wp = Wg + (size_t)(n0 + srow) * 512 + scb;
      for (int k0 = 0; k0 < 512; k0 += 32) {
        uint4 av = *(const uint4*)(ap + k0);
        uint4 wv = *(const uint4*)(wp + k0);
        __syncthreads();
        *(uint4*)&As[srow * 40 + scb] = av;
        *(uint4*)&B0[srow * 40 + scb] = wv;
        __syncthreads();
        bf16x8 a = *(const bf16x8*)&As[(w * 16 + l15) * 40 + q * 8];
        #pragma unroll
        for (int j = 0; j < 4; ++j) {
          bf16x8 b = *(const bf16x8*)&B0[(j * 16 + l15) * 40 + q * 8];
          acc[j] = __builtin_amdgcn_mfma_f32_16x16x32_bf16(a, b, acc[j], 0, 0, 0);
        }
      }
      #pragma unroll
      for (int j = 0; j < 4; ++j) {
        const int colL = cc * 64 + j * 16 + l15;
        const float bv = bg[n0 + j * 16 + l15];
        #pragma unroll
        for (int r = 0; r < 4; ++r) {
          const int row = w * 16 + q * 4 + r;
          zeL[row * 264 + colL] = f2b(fmaxf(acc[j][r] + bv, 0.f));
        }
      }
    }
    __syncthreads();  // zeL half complete (also guards B0 reuse below)
    // beta: stats partial over this half's K=256
    for (int kk = 0; kk < 8; ++kk) {
      const int gk = half * 256 + kk * 32;
      uint4 mv = *(const uint4*)(Wm + (size_t)srow * 512 + gk + scb);
      uint4 sv = *(const uint4*)(Ws + (size_t)srow * 512 + gk + scb);
      __syncthreads();
      *(uint4*)&B0[srow * 40 + scb] = mv;
      *(uint4*)&B1[srow * 40 + scb] = sv;
      __syncthreads();
      bf16x8 a = *(const bf16x8*)&zeL[(w * 16 + l15) * 264 + kk * 32 + q * 8];
      #pragma unroll
      for (int j = 0; j < 4; ++j) {
        bf16x8 b0 = *(const bf16x8*)&B0[(j * 16 + l15) * 40 + q * 8];
        bf16x8 b1 = *(const bf16x8*)&B1[(j * 16 + l15) * 40 + q * 8];
        accM[j] = __builtin_amdgcn_mfma_f32_16x16x32_bf16(a, b0, accM[j], 0, 0, 0);
        accS[j] = __builtin_amdgcn_mfma_f32_16x16x32_bf16(a, b1, accS[j], 0, 0, 0);
      }
    }
  }

  // epilogue: mu/sd per lane (C-layout)
  float kld = 0.0f;
  #pragma unroll
  for (int j = 0; j < 4; ++j) {
    const int c = j * 16 + l15;
    const float bmv = bm[c], bsv = bs[c];
    #pragma unroll
    for (int r = 0; r < 4; ++r) {
      const int row = w * 16 + q * 4 + r;
      const int m = m0 + row;
      const float mu = accM[j][r] + bmv;
      const float sd = splusf(accS[j][r] + bsv);
      if (!ENC) {
        o_pm[(size_t)m * Zn + c] = mu;
        o_ps[(size_t)m * Zn + c] = sd;
      } else {
        const float e = eps_t[(size_t)m * Zn + c];
        ztL[row * 72 + c] = f2b(e * sd + mu);
        const float pm = pm_in[(size_t)m * Zn + c];
        const float ps = ps_in[(size_t)m * Zn + c];
        const float dd = (mu - pm) / ps;
        const float rr = sd / ps;
        kld += dd * dd + rr * rr - 2.0f * __logf(rr) - 1.0f;
      }
    }
  }
  if (ENC) {
    const float s = block_sum(kld, red);   // contains __syncthreads -> ztL visible
    if (tid == 0) atomicAdd(kacc, 0.5f * s);
    // gamma: phiz = relu(zt @ pzW^T + pzb), K=64
    for (int cc = 0; cc < 8; ++cc) {
      f32x4 acc[4];
      #pragma unroll
      for (int j = 0; j < 4; ++j) acc[j] = (f32x4){0.f, 0.f, 0.f, 0.f};
      #pragma unroll
      for (int k0 = 0; k0 < 64; k0 += 32) {
        uint4 wv = *(const uint4*)(pzW + (size_t)(cc * 64 + srow) * 64 + k0 + scb);
        __syncthreads();
        *(uint4*)&B0[srow * 40 + scb] = wv;
        __syncthreads();
        bf16x8 a = *(const bf16x8*)&ztL[(w * 16 + l15) * 72 + k0 + q * 8];
        #pragma unroll
        for (int j = 0; j < 4; ++j) {
          bf16x8 b = *(const bf16x8*)&B0[(j * 16 + l15) * 40 + q * 8];
          acc[j] = __builtin_amdgcn_mfma_f32_16x16x32_bf16(a, b, acc[j], 0, 0, 0);
        }
      }
      #pragma unroll
      for (int j = 0; j < 4; ++j) {
        const int col = cc * 64 + j * 16 + l15;
        const float bz = pzb[col];
        #pragma unroll
        for (int r = 0; r < 4; ++r) {
          const int row = w * 16 + q * 4 + r;
          phiz_out[(size_t)(m0 + row) * 512 + col] = f2b(fmaxf(acc[j][r] + bz, 0.f));
        }
      }
    }
  }
}

// ================= kernels =================
__global__ __launch_bounds__(256) void k_gemm1(
    const us* A0, const us* W0, int ldw0, int K0,
    const float* bias, us* C, int ldc)
{
  __shared__ alignas(16) us sm[5120];
  tile_gemm<1, true>(blockIdx.x, blockIdx.y, A0, W0, ldw0, K0,
                     nullptr, nullptr, 0, 0, nullptr, nullptr, 0, 0, bias, C, ldc, sm);
}

__global__ __launch_bounds__(256) void k_gru1(
    const us* A0, const us* Wih, const us* hprev, const us* Whh,
    const float* bih, const float* bhh, us* hnew)
{
  __shared__ alignas(16) us sm[10240];
  tile_gru<1>(blockIdx.x, blockIdx.y, A0, nullptr, nullptr, Wih, Hn,
              hprev, Whh, bih, bhh, hnew, sm);
}

// f stats: f=eps*sd+mu -> fbuf(bf16), f_kld -> kacc
__global__ __launch_bounds__(256) void k_statf(
    const us* __restrict__ Ain, const us* __restrict__ Wm, const float* __restrict__ bm,
    const us* __restrict__ Ws, const float* __restrict__ bs,
    const float* __restrict__ eps, us* __restrict__ o0b, float* __restrict__ kacc)
{
  __shared__ alignas(16) us As[64 * 40];
  __shared__ alignas(16) us Ms[64 * 40];
  __shared__ alignas(16) us Ss[64 * 40];
  __shared__ float red[4];
  const int tid = threadIdx.x, srow = tid >> 2, scb = (tid & 3) * 8;
  const int lane = tid & 63, w = tid >> 6, l15 = lane & 15, q = lane >> 4;
  const int m0 = blockIdx.x * 64;
  f32x4 am[4], as_[4];
  #pragma unroll
  for (int j = 0; j < 4; ++j) { am[j] = (f32x4){0.f, 0.f, 0.f, 0.f}; as_[j] = am[j]; }
  const us* ap = Ain + (size_t)(m0 + srow) * Hn + scb;
  const us* mp = Wm + (size_t)srow * Hn + scb;
  const us* sp = Ws + (size_t)srow * Hn + scb;
  for (int k0 = 0; k0 < Hn; k0 += 32) {
    uint4 av = *(const uint4*)(ap + k0);
    uint4 mv = *(const uint4*)(mp + k0);
    uint4 sv = *(const uint4*)(sp + k0);
    __syncthreads();
    *(uint4*)&As[srow * 40 + scb] = av;
    *(uint4*)&Ms[srow * 40 + scb] = mv;
    *(uint4*)&Ss[srow * 40 + scb] = sv;
    __syncthreads();
    bf16x8 a = *(const bf16x8*)&As[(w * 16 + l15) * 40 + q * 8];
    #pragma unroll
    for (int j = 0; j < 4; ++j) {
      bf16x8 b0 = *(const bf16x8*)&Ms[(j * 16 + l15) * 40 + q * 8];
      bf16x8 b1 = *(const bf16x8*)&Ss[(j * 16 + l15) * 40 + q * 8];
      am[j]  = __builtin_amdgcn_mfma_f32_16x16x32_bf16(a, b0, am[j], 0, 0, 0);
      as_[j] = __builtin_amdgcn_mfma_f32_16x16x32_bf16(a, b1, as_[j], 0, 0, 0);
    }
  }
  float kld = 0.0f;
  #pragma unroll
  for (int j = 0; j < 4; ++j) {
    const int c = j * 16 + l15;
    const float bmv = bm[c], bsv = bs[c];
    #pragma unroll
    for (int r = 0; r < 4; ++r) {
      const int m = m0 + w * 16 + q * 4 + r;
      const float mu = am[j][r] + bmv;
      const float sd = splusf(as_[j][r] + bsv);
      o0b[(size_t)m * Zn + c] = f2b(eps[(size_t)m * Zn + c] * sd + mu);
      kld += mu * mu + sd * sd - 2.0f * __logf(sd) - 1.0f;
    }
  }
  const float s = block_sum(kld, red);
  if (tid == 0) atomicAdd(kacc, 0.5f * s);
}

// M1: dtmp(64) | gru(64)
__global__ __launch_bounds__(256) void megaM1(
    const us* phiz_r, const us* phi_f, const us* hcur, us* hnext, const us* px_t,
    const us* dW1, const float* db1, us* dtmp,
    const us* rWih, const us* rWhh, const float* rbih, const float* rbhh)
{
  __shared__ alignas(16) us sm[10240];
  const int b = blockIdx.x;
  if (b < 64)
    tile_gemm<3, true>(b & 7, b >> 3,
        phiz_r, dW1, 1536, 512, phi_f, dW1 + 512, 1536, 512, hcur, dW1 + 1024, 1536, 512,
        db1, dtmp, 512, sm);
  else
    tile_gru<3>((b - 64) & 7, (b - 64) >> 3, px_t, phiz_r, phi_f,
                rWih, 1536, hcur, rWhh, rbih, rbhh, hnext, sm);
}

// M2: dec(64) | prior_tall(8) | zepre'(64)
__global__ __launch_bounds__(256) void megaM2(
    const us* dtmp, const us* dW2, const float* db2, us* dec,
    const us* hnext, const us* zpW, const float* zpb,
    const us* zpmW, const float* zpmb, const us* zpsW, const float* zpsb,
    float* zpm, float* zps,
    const us* px_next, const us* zeW1, const float* zeb1, us* zepre)
{
  __shared__ alignas(16) char sm[58400];
  const int b = blockIdx.x;
  if (b < 64)
    tile_gemm<1, true>(b & 7, b >> 3, dtmp, dW2, 512, 512,
        nullptr, nullptr, 0, 0, nullptr, nullptr, 0, 0, db2, dec, 512, (us*)sm);
  else if (b < 72)
    tall_stat<false>(b - 64, hnext, zpW, zpb, zpmW, zpmb, zpsW, zpsb,
        nullptr, nullptr, nullptr, zpm, zps, nullptr, nullptr, nullptr, nullptr, sm);
  else
    tile_gemm<2, true>((b - 72) & 7, (b - 72) >> 3,
        px_next, zeW1, 1024, 512, hnext, zeW1 + 512, 1024, 512, nullptr, nullptr, 0, 0,
        zeb1, zepre, 512, (us*)sm);
}

// M3: nll(104) | enc_tall(8)
__global__ __launch_bounds__(256) void megaM3(
    const us* dec, const us* dmW, const float* dmb, const float* xt, float* nll,
    const us* zepre, const us* zeW2, const float* zeb2,
    const us* zemW, const float* zemb, const us* zesW, const float* zesb,
    const float* eps_next, const float* zpm, const float* zps,
    const us* pzW, const float* pzb, us* phiz_w, float* kacc)
{
  __shared__ alignas(16) char sm[58400];
  const int b = blockIdx.x;
  if (b < 104)
    tile_nll(b % 13, b / 13, dec, dmW, dmb, xt, nll, sm);
  else
    tall_stat<true>(b - 104, zepre, zeW2, zeb2, zemW, zemb, zesW, zesb,
        eps_next, zpm, zps, nullptr, nullptr, pzW, pzb, phiz_w, kacc, sm);
}

// P1: phi_f gemm(64) | prior_tall(8, h0) | zepre0(64)
__global__ __launch_bounds__(256) void megaP1(
    const us* fbuf, const us* pfW, const float* pfb, us* phi_f,
    const us* h0, const us* zpW, const float* zpb,
    const us* zpmW, const float* zpmb, const us* zpsW, const float* zpsb,
    float* zpm, float* zps,
    const us* px0, const us* zeW1, const float* zeb1, us* zepre)
{
  __shared__ alignas(16) char sm[58400];
  const int b = blockIdx.x;
  if (b < 64)
    tile_gemm<1, true>(b & 7, b >> 3, fbuf, pfW, 64, 64,
        nullptr, nullptr, 0, 0, nullptr, nullptr, 0, 0, pfb, phi_f, 512, (us*)sm);
  else if (b < 72)
    tall_stat<false>(b - 64, h0, zpW, zpb, zpmW, zpmb, zpsW, zpsb,
        nullptr, nullptr, nullptr, zpm, zps, nullptr, nullptr, nullptr, nullptr, sm);
  else
    tile_gemm<2, true>((b - 72) & 7, (b - 72) >> 3,
        px0, zeW1, 1024, 512, h0, zeW1 + 512, 1024, 512, nullptr, nullptr, 0, 0,
        zeb1, zepre, 512, (us*)sm);
}

// P2: enc_tall only (8 blocks)
__global__ __launch_bounds__(256) void megaP2(
    const us* zepre, const us* zeW2, const float* zeb2,
    const us* zemW, const float* zemb, const us* zesW, const float* zesb,
    const float* eps0, const float* zpm, const float* zps,
    const us* pzW, const float* pzb, us* phiz_w, float* kacc)
{
  __shared__ alignas(16) char sm[58400];
  tall_stat<true>(blockIdx.x, zepre, zeW2, zeb2, zemW, zemb, zesW, zesb,
      eps0, zpm, zps, nullptr, nullptr, pzW, pzb, phiz_w, kacc, sm);
}

} // anonymous namespace

extern "C" void kernel_launch(void* const* d_in, const int* in_sizes, int n_in,
                              void* d_out, int out_size, void* d_ws, size_t ws_size,
                              hipStream_t stream)
{
  (void)in_sizes; (void)n_in; (void)out_size;
  const float* x     = (const float*)d_in[0];
  const float* eps_f = (const float*)d_in[1];
  const float* eps_z = (const float*)d_in[2];
  const float* pxW1  = (const float*)d_in[3];
  const float* pxb1  = (const float*)d_in[4];
  const float* pxW2  = (const float*)d_in[5];
  const float* pxb2  = (const float*)d_in[6];
  const float* pzW   = (const float*)d_in[7];
  const float* pzb   = (const float*)d_in[8];
  const float* pfW   = (const float*)d_in[9];
  const float* pfb   = (const float*)d_in[10];
  const float* rWih  = (const float*)d_in[11];
  const float* rWhh  = (const float*)d_in[12];
  const float* rbih  = (const float*)d_in[13];
  const float* rbhh  = (const float*)d_in[14];
  const float* zpW   = (const float*)d_in[15];
  const float* zpb   = (const float*)d_in[16];
  const float* zpmW  = (const float*)d_in[17];
  const float* zpmb  = (const float*)d_in[18];
  const float* zpsW  = (const float*)d_in[19];
  const float* zpsb  = (const float*)d_in[20];
  const float* feWih = (const float*)d_in[21];
  const float* feWhh = (const float*)d_in[22];
  const float* febih = (const float*)d_in[23];
  const float* febhh = (const float*)d_in[24];
  const float* femW  = (const float*)d_in[25];
  const float* femb  = (const float*)d_in[26];
  const float* fesW  = (const float*)d_in[27];
  const float* fesb  = (const float*)d_in[28];
  const float* zeW1  = (const float*)d_in[29];
  const float* zeb1  = (const float*)d_in[30];
  const float* zeW2  = (const float*)d_in[31];
  const float* zeb2  = (const float*)d_in[32];
  const float* zemW  = (const float*)d_in[33];
  const float* zemb  = (const float*)d_in[34];
  const float* zesW  = (const float*)d_in[35];
  const float* zesb  = (const float*)d_in[36];
  const float* dW1   = (const float*)d_in[37];
  const float* db1   = (const float*)d_in[38];
  const float* dW2   = (const float*)d_in[39];
  const float* db2   = (const float*)d_in[40];
  const float* dmW   = (const float*)d_in[41];
  const float* dmb   = (const float*)d_in[42];
  float* out = (float*)d_out;

  char* base = (char*)d_ws;
  size_t off = 0;
  auto ab = [&](size_t bytes) -> void* {
    void* p = base + off;
    off += (bytes + 255) & ~(size_t)255;
    return p;
  };

  // bf16 weights
  us* b_pxW1  = (us*)ab((size_t)512 * XnP * 2);
  us* b_pxW2  = (us*)ab((size_t)512 * 512 * 2);
  us* b_pzW   = (us*)ab((size_t)512 * 64 * 2);
  us* b_pfW   = (us*)ab((size_t)512 * 64 * 2);
  us* b_rWih  = (us*)ab((size_t)1536 * 1536 * 2);
  us* b_rWhh  = (us*)ab((size_t)1536 * 512 * 2);
  us* b_zpW   = (us*)ab((size_t)512 * 512 * 2);
  us* b_zpmW  = (us*)ab((size_t)64 * 512 * 2);
  us* b_zpsW  = (us*)ab((size_t)64 * 512 * 2);
  us* b_feWih = (us*)ab((size_t)1536 * 512 * 2);
  us* b_feWhh = (us*)ab((size_t)1536 * 512 * 2);
  us* b_femW  = (us*)ab((size_t)64 * 512 * 2);
  us* b_fesW  = (us*)ab((size_t)64 * 512 * 2);
  us* b_zeW1  = (us*)ab((size_t)512 * 1024 * 2);
  us* b_zeW2  = (us*)ab((size_t)512 * 512 * 2);
  us* b_zemW  = (us*)ab((size_t)64 * 512 * 2);
  us* b_zesW  = (us*)ab((size_t)64 * 512 * 2);
  us* b_dW1   = (us*)ab((size_t)512 * 1536 * 2);
  us* b_dW2   = (us*)ab((size_t)512 * 512 * 2);
  us* b_dmW   = (us*)ab((size_t)Xn * 512 * 2);

  // activations
  us* phi_x = (us*)ab((size_t)Tn * Bn * Hn * 2);
  us* fh_a  = (us*)ab((size_t)Bn * Hn * 2);
  us* h_a   = (us*)ab((size_t)Bn * Hn * 2);   // adjacent to fh_a (one memset)
  us* fh_b  = (us*)ab((size_t)Bn * Hn * 2);
  us* h_b   = (us*)ab((size_t)Bn * Hn * 2);
  us* fbuf  = (us*)ab((size_t)Bn * Fn * 2);
  us* phi_f = (us*)ab((size_t)Bn * Hn * 2);
  us* zepre = (us*)ab((size_t)Bn * Hn * 2);
  us* dtmp  = (us*)ab((size_t)Bn * Hn * 2);
  us* dec   = (us*)ab((size_t)Bn * Hn * 2);
  us* phiz0 = (us*)ab((size_t)Bn * Hn * 2);
  us* phiz1 = (us*)ab((size_t)Bn * Hn * 2);
  float* zpm = (float*)ab((size_t)Bn * Zn * 4);
  float* zps = (float*)ab((size_t)Bn * Zn * 4);

  int CH = 16;
  while (CH > 1 && off + (size_t)CH * (Bn * XnP + Bn * Hn) * 2 + 4096 > ws_size) CH >>= 1;
  us* xch  = (us*)ab((size_t)CH * Bn * XnP * 2);
  us* tmpb = (us*)ab((size_t)CH * Bn * Hn * 2);

  hipMemsetAsync(d_out, 0, 3 * sizeof(float), stream);
  hipMemsetAsync(fh_a, 0, 2 * (size_t)Bn * Hn * 2, stream);  // fh_a + h_a

  const dim3 blk(256);
  auto CVT = [&](const float* s, us* d, size_t n) {
    cvt<<<dim3((unsigned)((n + 255) / 256)), blk, 0, stream>>>(s, d, (int)n);
  };

  {
    const size_t n = (size_t)512 * XnP;
    cvt_pad<<<dim3((unsigned)((n + 255) / 256)), blk, 0, stream>>>(pxW1, b_pxW1, Xn, XnP, (int)n);
  }
  CVT(pxW2, b_pxW2, (size_t)512 * 512);
  CVT(pzW, b_pzW, (size_t)512 * 64);
  CVT(pfW, b_pfW, (size_t)512 * 64);
  CVT(rWih, b_rWih, (size_t)1536 * 1536);
  CVT(rWhh, b_rWhh, (size_t)1536 * 512);
  CVT(zpW, b_zpW, (size_t)512 * 512);
  CVT(zpmW, b_zpmW, (size_t)64 * 512);
  CVT(zpsW, b_zpsW, (size_t)64 * 512);
  CVT(feWih, b_feWih, (size_t)1536 * 512);
  CVT(feWhh, b_feWhh, (size_t)1536 * 512);
  CVT(femW, b_femW, (size_t)64 * 512);
  CVT(fesW, b_fesW, (size_t)64 * 512);
  CVT(zeW1, b_zeW1, (size_t)512 * 1024);
  CVT(zeW2, b_zeW2, (size_t)512 * 512);
  CVT(zemW, b_zemW, (size_t)64 * 512);
  CVT(zesW, b_zesW, (size_t)64 * 512);
  CVT(dW1, b_dW1, (size_t)512 * 1536);
  CVT(dW2, b_dW2, (size_t)512 * 512);
  CVT(dmW, b_dmW, (size_t)Xn * 512);

  // Phase A: phi_x
  for (int c = 0; c < Tn / CH; ++c) {
    const size_t nx = (size_t)CH * Bn * XnP;
    cvt_pad<<<dim3((unsigned)((nx + 255) / 256)), blk, 0, stream>>>(
        x + (size_t)c * CH * Bn * Xn, xch, Xn, XnP, (int)nx);
    const dim3 gA(8, CH * Bn / 64);
    k_gemm1<<<gA, blk, 0, stream>>>(xch, b_pxW1, XnP, XnP, pxb1, tmpb, Hn);
    k_gemm1<<<gA, blk, 0, stream>>>(tmpb, b_pxW2, Hn, Hn, pxb2,
                                    phi_x + (size_t)c * CH * Bn * Hn, Hn);
  }

  // Phase B: f-encoder GRU
  us* fc = fh_a; us* fn = fh_b;
  for (int t = 0; t < Tn; ++t) {
    k_gru1<<<dim3(8, 8), blk, 0, stream>>>(
        phi_x + (size_t)t * Bn * Hn, b_feWih, fc, b_feWhh, febih, febhh, fn);
    us* sw = fc; fc = fn; fn = sw;
  }

  // Phase C: f stats
  k_statf<<<dim3(8), blk, 0, stream>>>(fc, b_femW, femb, b_fesW, fesb, eps_f, fbuf, out + 0);

  // Prologue
  megaP1<<<dim3(136), blk, 0, stream>>>(
      fbuf, b_pfW, pfb, phi_f, h_a, b_zpW, zpb, b_zpmW, zpmb, b_zpsW, zpsb,
      zpm, zps, phi_x, b_zeW1, zeb1, zepre);
  megaP2<<<dim3(8), blk, 0, stream>>>(
      zepre, b_zeW2, zeb2, b_zemW, zemb, b_zesW, zesb, eps_z, zpm, zps,
      b_pzW, pzb, phiz0, out + 1);

  // Phase D main loop: 3 launches per timestep
  us* phizA[2] = {phiz0, phiz1};
  for (int t = 0; t < Tn; ++t) {
    const us* hcur = (t & 1) ? h_b : h_a;
    us* hnext      = (t & 1) ? h_a : h_b;
    const us* phir = phizA[t & 1];
    us* phiw       = phizA[(t + 1) & 1];
    const bool last = (t == Tn - 1);

    megaM1<<<dim3(128), blk, 0, stream>>>(
        phir, phi_f, hcur, hnext, phi_x + (size_t)t * Bn * Hn,
        b_dW1, db1, dtmp, b_rWih, b_rWhh, rbih, rbhh);

    megaM2<<<dim3(last ? 64 : 136), blk, 0, stream>>>(
        dtmp, b_dW2, db2, dec, hnext, b_zpW, zpb, b_zpmW, zpmb, b_zpsW, zpsb,
        zpm, zps, phi_x + (size_t)(t + 1) * Bn * Hn, b_zeW1, zeb1, zepre);

    megaM3<<<dim3(last ? 104 : 112), blk, 0, stream>>>(
        dec, b_dmW, dmb, x + (size_t)t * Bn * Xn, out + 2,
        zepre, b_zeW2, zeb2, b_zemW, zemb, b_zesW, zesb,
        eps_z + (size_t)(t + 1) * Bn * Zn, zpm, zps, b_pzW, pzb, phiw, out + 1);
  }
}